// Round 20
// baseline (201.721 us; speedup 1.0000x reference)
//
#include <hip/hip_runtime.h>

typedef __attribute__((ext_vector_type(4))) float f32x4;
typedef __attribute__((ext_vector_type(16))) float f32x16;
typedef __attribute__((ext_vector_type(8))) short bf16x8;
typedef __attribute__((ext_vector_type(4))) unsigned u32x4;

__device__ __forceinline__ unsigned short f2bf(float f) {
  unsigned u = __float_as_uint(f);
  u += 0x7fff + ((u >> 16) & 1);   // round-to-nearest-even
  return (unsigned short)(u >> 16);
}
__device__ __forceinline__ float bf2f(unsigned short h) {
  return __uint_as_float(((unsigned)h) << 16);
}

__device__ __forceinline__ void gload_lds16(const void* g, void* lds) {
  __builtin_amdgcn_global_load_lds(
      (const __attribute__((address_space(1))) unsigned int*)g,
      (__attribute__((address_space(3))) unsigned int*)lds, 16, 0, 0);
}

// ------------------------------------------------- fused cast f32->bf16 + RoPE table
__global__ void cast3_rope_tbl(const float* __restrict__ x,
                               const float* __restrict__ wq,
                               const float* __restrict__ wo,
                               unsigned short* __restrict__ xb,
                               unsigned short* __restrict__ wqb,
                               unsigned short* __restrict__ wob,
                               float2* __restrict__ cs) {
  if (blockIdx.x >= 12288) {
    int idx = (blockIdx.x - 12288) * blockDim.x + threadIdx.x;  // 0..65535
    int t = idx >> 5, i = idx & 31;
    float inv = powf(10000.0f, -(float)(2 * i) / 64.0f);
    float a = (float)t * inv;
    cs[idx] = make_float2(cosf(a), sinf(a));
    return;
  }
  int i = blockIdx.x * blockDim.x + threadIdx.x;  // 0..3145727 (float4 units)
  const float* src;
  unsigned short* dst;
  int off;
  if (i < 2097152) { src = x;  dst = xb;  off = i; }
  else if (i < 2883584) { src = wq; dst = wqb; off = i - 2097152; }
  else { src = wo; dst = wob; off = i - 2883584; }
  float4 v = ((const float4*)src)[off];
  ushort4 o;
  o.x = f2bf(v.x); o.y = f2bf(v.y); o.z = f2bf(v.z); o.w = f2bf(v.w);
  ((ushort4*)dst)[off] = o;
}

// ---------------------------------------------------------------- RoPE apply (K only, in-place)
__global__ void rope_apply_k(unsigned short* __restrict__ qkv,
                             const float2* __restrict__ cs) {
  int idx = blockIdx.x * blockDim.x + threadIdx.x;  // 1048576
  int i4 = idx & 7;
  int h = (idx >> 3) & 15;
  int t = (idx >> 7) & 2047;
  int b = idx >> 18;
  unsigned short* p =
      qkv + ((size_t)((b << 11) + t)) * 3072 + 1024 + h * 64 + i4 * 8;
  bf16x8 v = *(const bf16x8*)p;
  const float2* c4 = cs + (t << 5) + i4 * 4;
#pragma unroll
  for (int j = 0; j < 4; ++j) {
    const float2 cn = c4[j];
    const float e = bf2f((unsigned short)v[2 * j]);
    const float o = bf2f((unsigned short)v[2 * j + 1]);
    v[2 * j]     = (short)f2bf(e * cn.x - o * cn.y);
    v[2 * j + 1] = (short)f2bf(e * cn.y + o * cn.x);
  }
  *(bf16x8*)p = v;
}

// ---------------------------------------------------------------- GEMM phased: counted-vmcnt ring
template <int OUT_BF16>
__global__ __launch_bounds__(512, 2) void gemm_bt_p(
    const unsigned short* __restrict__ A, const unsigned short* __restrict__ B,
    const float* __restrict__ bias, void* __restrict__ Cout,
    int M, int N, int K) {
  __shared__ unsigned short lA[3 * 8192];   // 3 x 128 lines x 64 elems (16 KB)
  __shared__ unsigned short lB[3 * 4096];   // 3 x  64 lines x 64 elems ( 8 KB)

  const int tiles_n = N >> 7;
  const int swz = (blockIdx.x & 7) * (gridDim.x >> 3) + (blockIdx.x >> 3);
  const int bm = swz / tiles_n;
  const int bn = swz % tiles_n;
  const int m0 = bm << 8, n0 = bn << 7;
  const int tid = threadIdx.x;
  const int w = tid >> 6, l = tid & 63;
  const int l15 = l & 15, lq = l >> 4;      // lq 0..3
  const int wm = w >> 2, wn = w & 3;        // 2 x 4 waves

  const int sl8 = l >> 3, sc = l & 7;       // staging: lane row/chunk in 8x8

  f32x4 acc[8][2] = {};

#define STAGE_HALF(J, RS)                                                     \
  if ((J) < 32) {                                                             \
    const int k0_ = (J) * 32;                                                 \
    _Pragma("unroll")                                                         \
    for (int i_ = 0; i_ < 2; ++i_) {                                          \
      const int line = i_ * 64 + w * 8 + sl8;                                 \
      const int lc = sc ^ (line & 7);                                         \
      const int row = 2 * line + (lc >> 2);                                   \
      gload_lds16(A + (size_t)(m0 + row) * K + k0_ + (lc & 3) * 8,            \
                  &lA[(RS) * 8192 + line * 64 + sc * 8]);                     \
    }                                                                         \
    {                                                                         \
      const int line = w * 8 + sl8;                                           \
      const int lc = sc ^ (line & 7);                                         \
      const int row = 2 * line + (lc >> 2);                                   \
      gload_lds16(B + (size_t)(n0 + row) * K + k0_ + (lc & 3) * 8,            \
                  &lB[(RS) * 4096 + line * 64 + sc * 8]);                     \
    }                                                                         \
  }

  STAGE_HALF(0, 0);
  STAGE_HALF(1, 1);

  int rb = 0;          // ring slot of half j
  for (int j = 0; j < 32; ++j) {
    if (j < 31)
      asm volatile("s_waitcnt vmcnt(3)" ::: "memory");
    else
      asm volatile("s_waitcnt vmcnt(0)" ::: "memory");
    __builtin_amdgcn_s_barrier();

    bf16x8 af[8], bfr[2];
#pragma unroll
    for (int mi = 0; mi < 8; ++mi) {
      const int row = wm * 128 + mi * 16 + l15;
      const int line = row >> 1;
      const int pc = (((row & 1) * 4 + lq) ^ (line & 7));
      af[mi] = *(const bf16x8*)&lA[rb * 8192 + line * 64 + pc * 8];
    }
#pragma unroll
    for (int ni = 0; ni < 2; ++ni) {
      const int row = wn * 32 + ni * 16 + l15;
      const int line = row >> 1;
      const int pc = (((row & 1) * 4 + lq) ^ (line & 7));
      bfr[ni] = *(const bf16x8*)&lB[rb * 4096 + line * 64 + pc * 8];
    }

    const int rs = rb == 0 ? 2 : rb - 1;    // (rb+2)%3
    STAGE_HALF(j + 2, rs);

    __builtin_amdgcn_s_setprio(1);
#pragma unroll
    for (int mi = 0; mi < 8; ++mi)
#pragma unroll
      for (int ni = 0; ni < 2; ++ni)
        acc[mi][ni] = __builtin_amdgcn_mfma_f32_16x16x32_bf16(
            af[mi], bfr[ni], acc[mi][ni], 0, 0, 0);
    __builtin_amdgcn_s_setprio(0);

    rb = rb == 2 ? 0 : rb + 1;
  }
#undef STAGE_HALF

#pragma unroll
  for (int ni = 0; ni < 2; ++ni) {
    const int c = n0 + wn * 32 + ni * 16 + l15;
    const float bv = bias[c];
#pragma unroll
    for (int mi = 0; mi < 8; ++mi) {
#pragma unroll
      for (int jj = 0; jj < 4; ++jj) {
        const int r = m0 + wm * 128 + mi * 16 + lq * 4 + jj;
        const float v = acc[mi][ni][jj] + bv;
        if (OUT_BF16)
          ((unsigned short*)Cout)[(size_t)r * N + c] = f2bf(v);
        else
          ((float*)Cout)[(size_t)r * N + c] = v;
      }
    }
  }
}

// ---------------------------------------------------------------- flash attention fwd
// v20 = v17 with the 64-row K tile processed as TWO 32-row S subtiles,
// each consumed before the next (one 16-reg S live at a time -> 4 waves/SIMD).
#define PACKPV(SCV, KS)                                                        \
  do {                                                                         \
    unsigned xa, xb, ya, yb;                                                   \
    asm("v_cvt_pk_bf16_f32 %0, %1, %2"                                         \
        : "=v"(xa) : "v"(SCV[((KS) & 1) * 8 + 0]), "v"(SCV[((KS) & 1) * 8 + 1])); \
    asm("v_cvt_pk_bf16_f32 %0, %1, %2"                                         \
        : "=v"(xb) : "v"(SCV[((KS) & 1) * 8 + 2]), "v"(SCV[((KS) & 1) * 8 + 3])); \
    asm("v_cvt_pk_bf16_f32 %0, %1, %2"                                         \
        : "=v"(ya) : "v"(SCV[((KS) & 1) * 8 + 4]), "v"(SCV[((KS) & 1) * 8 + 5])); \
    asm("v_cvt_pk_bf16_f32 %0, %1, %2"                                         \
        : "=v"(yb) : "v"(SCV[((KS) & 1) * 8 + 6]), "v"(SCV[((KS) & 1) * 8 + 7])); \
    asm("v_permlane32_swap_b32 %0, %1" : "+v"(xa), "+v"(ya));                  \
    asm("v_permlane32_swap_b32 %0, %1" : "+v"(xb), "+v"(yb));                  \
    u32x4 pw;                                                                  \
    pw[0] = xa; pw[1] = xb; pw[2] = ya; pw[3] = yb;                            \
    const bf16x8 pa = __builtin_bit_cast(bf16x8, pw);                          \
    {                                                                          \
      const bf16x8 vf = *(const bf16x8*)                                       \
          &lVc[l31 * 72 + ((16 * (KS) + 8 * hi) ^ (l31 & 0x38))];              \
      o0 = __builtin_amdgcn_mfma_f32_32x32x16_bf16(pa, vf, o0, 0, 0, 0);       \
    }                                                                          \
    {                                                                          \
      const int vrow = 32 + l31;                                               \
      const bf16x8 vf = *(const bf16x8*)                                       \
          &lVc[vrow * 72 + ((16 * (KS) + 8 * hi) ^ (vrow & 0x38))];            \
      o1 = __builtin_amdgcn_mfma_f32_32x32x16_bf16(pa, vf, o1, 0, 0, 0);       \
    }                                                                          \
  } while (0)

// one 32-row subtile: S = K*Q, softmax-merge, PACKPV x2.  KR = k-row base
// within tile (0 or 32); KS0 = 2*(KR/32).
#define SUBTILE(KR, KS0)                                                       \
  do {                                                                         \
    f32x16 s = {};                                                             \
    __builtin_amdgcn_s_setprio(1);                                             \
    _Pragma("unroll")                                                          \
    for (int ss = 0; ss < 4; ++ss) {                                           \
      bf16x8 kf = *(const bf16x8*)                                             \
          &lKc[((KR) + l31) * 64 + (((2 * ss + hi) ^ l7) << 3)];               \
      s = __builtin_amdgcn_mfma_f32_32x32x16_bf16(kf, qf[ss], s, 0, 0, 0);     \
    }                                                                          \
    __builtin_amdgcn_s_setprio(0);                                             \
    float pmax = -1e30f;                                                       \
    _Pragma("unroll")                                                          \
    for (int r = 0; r < 16; r += 2) {                                          \
      float t0;                                                                \
      asm("v_max3_f32 %0, %1, %2, %3"                                          \
          : "=v"(t0) : "v"(s[r]), "v"(s[r + 1]), "v"(pmax));                   \
      pmax = t0;                                                               \
    }                                                                          \
    pmax = fmaxf(pmax, __shfl_xor(pmax, 32));                                  \
    if (!__all(pmax <= m_run + 8.0f)) {                                        \
      const float mn = fmaxf(m_run, pmax);                                     \
      const float alpha = __expf(m_run - mn);                                  \
      m_run = mn;                                                              \
      lsum *= alpha;                                                           \
      _Pragma("unroll")                                                        \
      for (int r = 0; r < 16; ++r) {                                           \
        const float ar = __shfl(alpha, (r & 3) + 8 * (r >> 2) + 4 * hi);       \
        o0[r] *= ar;                                                           \
        o1[r] *= ar;                                                           \
      }                                                                        \
    }                                                                          \
    const float m2 = m_run * L2E;                                              \
    float rsa = 0.f, rsb = 0.f;                                                \
    _Pragma("unroll")                                                          \
    for (int r = 0; r < 16; r += 2) {                                          \
      float a0 = __builtin_fmaf(s[r], L2E, -m2);                               \
      float a1 = __builtin_fmaf(s[r + 1], L2E, -m2);                           \
      float p0, p1;                                                            \
      asm("v_exp_f32 %0, %1" : "=v"(p0) : "v"(a0));                            \
      asm("v_exp_f32 %0, %1" : "=v"(p1) : "v"(a1));                            \
      s[r] = p0; s[r + 1] = p1;                                                \
      rsa += p0; rsb += p1;                                                    \
    }                                                                          \
    float rsl = rsa + rsb;                                                     \
    rsl += __shfl_xor(rsl, 32);                                                \
    lsum += rsl;                                                               \
    __builtin_amdgcn_s_setprio(1);                                             \
    PACKPV(s, (KS0));                                                          \
    PACKPV(s, (KS0) + 1);                                                      \
    __builtin_amdgcn_s_setprio(0);                                             \
  } while (0)

__global__ __launch_bounds__(512, 4) void attn_fwd(
    const unsigned short* __restrict__ qkv, unsigned short* __restrict__ aout,
    const float2* __restrict__ cs) {
  __shared__ unsigned short lK[2 * 64 * 64];    // K tiles, chunk-XOR-swizzled
  __shared__ unsigned short lVt[2 * 64 * 72];   // V^T, stride 72, k ^ (d&0x38)

  const int g = blockIdx.x;
  const int xcd = g & 7;
  const int j2 = g >> 3;                 // 0..63
  const int bh = ((j2 >> 3) << 3) + xcd; // 0..63
  const int qt = j2 & 7;
  const int h = bh & 15, b = bh >> 4;

  const int tid = threadIdx.x;
  const int w = tid >> 6, l = tid & 63;  // 8 waves
  const int l31 = l & 31, hi = l >> 5;
  const int l7 = l & 7;

  const size_t bt_base = (size_t)(b * 2048) * 3072;
  const int qbase = qt * 256 + w * 32;

  const unsigned short* Qp =
      qkv + bt_base + (size_t)(qbase + l31) * 3072 + h * 64 + hi * 8;
  const float2* csrow = cs + (size_t)(qbase + l31) * 32;
  bf16x8 qf[4];
#pragma unroll
  for (int s = 0; s < 4; ++s) {
    bf16x8 q = *(const bf16x8*)(Qp + 16 * s);
#pragma unroll
    for (int j = 0; j < 4; ++j) {
      const float2 cn = csrow[8 * s + 4 * hi + j];
      const float e = bf2f((unsigned short)q[2 * j]);
      const float o = bf2f((unsigned short)q[2 * j + 1]);
      q[2 * j]     = (short)f2bf((e * cn.x - o * cn.y) * 0.125f);
      q[2 * j + 1] = (short)f2bf((e * cn.y + o * cn.x) * 0.125f);
    }
    qf[s] = q;
  }

  const unsigned short* Kp = qkv + bt_base + 1024 + h * 64;
  const unsigned short* Vp = qkv + bt_base + 2048 + h * 64;

  const int krow = l >> 3;
  const int kcol = ((l & 7) ^ (l >> 3)) << 3;

  const int vr = tid >> 3;             // 0..63
  const int vc0 = (tid & 7) << 3;      // 0,8,..,56
  const int vx = vc0;                  // write swizzle: k ^ (d & 0x38)

  f32x16 o0 = {}, o1 = {};
  float m_run = -1e30f, lsum = 0.f;
  bf16x8 v0;
  const float L2E = 1.4426950408889634f;

  {
    gload_lds16(Kp + (size_t)(w * 8 + krow) * 3072 + kcol, &lK[(w * 8) * 64]);
    const unsigned short* vb = Vp + (size_t)vr * 3072 + vc0;
    v0 = *(const bf16x8*)vb;
  }
  __syncthreads();
#pragma unroll
  for (int i2 = 0; i2 < 8; ++i2)
    lVt[(vc0 + i2) * 72 + (vr ^ vx)] = (unsigned short)v0[i2];
  __syncthreads();

  for (int t = 0; t < 32; ++t) {
    const int cur = t & 1;
    const unsigned short* lKc = lK + cur * 4096;
    const unsigned short* lVc = lVt + cur * 4608;
    const bool stage = (t < 31);

    if (stage) {
      const unsigned short* kb = Kp + (size_t)(t + 1) * 64 * 3072;
      gload_lds16(kb + (size_t)(w * 8 + krow) * 3072 + kcol,
                  lK + (cur ^ 1) * 4096 + (w * 8) * 64);
    }

    // subtile 0 (k-rows 0..31 of tile)
    SUBTILE(0, 0);

    if (stage) {
      const unsigned short* vb =
          Vp + (size_t)(t + 1) * 64 * 3072 + (size_t)vr * 3072 + vc0;
      v0 = *(const bf16x8*)vb;
    }

    // subtile 1 (k-rows 32..63 of tile)
    SUBTILE(32, 2);

    if (stage) {
      unsigned short* lVn = lVt + (cur ^ 1) * 4608;
#pragma unroll
      for (int i2 = 0; i2 < 8; ++i2)
        lVn[(vc0 + i2) * 72 + (vr ^ vx)] = (unsigned short)v0[i2];
    }
    __syncthreads();
  }

  const float linv = 1.0f / lsum;
#pragma unroll
  for (int r = 0; r < 16; ++r) {
    const int crow = (r & 3) + 8 * (r >> 2) + 4 * hi;
    const float lr = __shfl(linv, crow);
    unsigned short* orow =
        aout + (size_t)(b * 2048 + qbase + crow) * 1024 + h * 64 + l31;
    orow[0] = f2bf(o0[r] * lr);
    orow[32] = f2bf(o1[r] * lr);
  }
}

// ---------------------------------------------------------------- launch
extern "C" void kernel_launch(void* const* d_in, const int* in_sizes, int n_in,
                              void* d_out, int out_size, void* d_ws, size_t ws_size,
                              hipStream_t stream) {
  const float* x     = (const float*)d_in[0];
  const float* w_qkv = (const float*)d_in[1];
  const float* b_qkv = (const float*)d_in[2];
  const float* w_out = (const float*)d_in[3];
  const float* b_out = (const float*)d_in[4];
  float* out = (float*)d_out;

  char* ws = (char*)d_ws;
  unsigned short* x_bf    = (unsigned short*)(ws);             // 16 MB
  unsigned short* wqkv_bf = (unsigned short*)(ws + 16777216);  // 6 MB
  unsigned short* wout_bf = (unsigned short*)(ws + 23068672);  // 2 MB
  unsigned short* qkv     = (unsigned short*)(ws + 25165824);  // 48 MB
  unsigned short* aout    = (unsigned short*)(ws + 75497472);  // 16 MB
  float2* cs              = (float2*)(ws + 92274688);          // 512 KB

  cast3_rope_tbl<<<12544, 256, 0, stream>>>(x, w_qkv, w_out,
                                            x_bf, wqkv_bf, wout_bf, cs);

  // qkv = x @ w_qkv^T + b_qkv  (M=8192, N=3072, K=1024) — phased, 768 blocks
  gemm_bt_p<1><<<768, 512, 0, stream>>>(x_bf, wqkv_bf, b_qkv, qkv,
                                        8192, 3072, 1024);
  rope_apply_k<<<1048576 / 256, 256, 0, stream>>>(qkv, cs);
  attn_fwd<<<512, 512, 0, stream>>>(qkv, aout, cs);
  // out = attn @ w_out^T + b_out (M=8192, N=1024, K=1024) — phased, 256 blocks
  gemm_bt_p<0><<<256, 512, 0, stream>>>(aout, wout_bf, b_out, out,
                                        8192, 1024, 1024);
}

// Round 21
// 198.509 us; speedup vs baseline: 1.0162x; 1.0162x over previous
//
#include <hip/hip_runtime.h>

typedef __attribute__((ext_vector_type(4))) float f32x4;
typedef __attribute__((ext_vector_type(16))) float f32x16;
typedef __attribute__((ext_vector_type(8))) short bf16x8;
typedef __attribute__((ext_vector_type(4))) unsigned u32x4;

__device__ __forceinline__ unsigned short f2bf(float f) {
  unsigned u = __float_as_uint(f);
  u += 0x7fff + ((u >> 16) & 1);   // round-to-nearest-even
  return (unsigned short)(u >> 16);
}
__device__ __forceinline__ float bf2f(unsigned short h) {
  return __uint_as_float(((unsigned)h) << 16);
}

__device__ __forceinline__ void gload_lds16(const void* g, void* lds) {
  __builtin_amdgcn_global_load_lds(
      (const __attribute__((address_space(1))) unsigned int*)g,
      (__attribute__((address_space(3))) unsigned int*)lds, 16, 0, 0);
}

// ------------------------------------------------- fused cast f32->bf16 + RoPE table
// blocks [0,12288): cast x/w_qkv/w_out; blocks [12288,12544): cos/sin table
__global__ void cast3_rope_tbl(const float* __restrict__ x,
                               const float* __restrict__ wq,
                               const float* __restrict__ wo,
                               unsigned short* __restrict__ xb,
                               unsigned short* __restrict__ wqb,
                               unsigned short* __restrict__ wob,
                               float2* __restrict__ cs) {
  if (blockIdx.x >= 12288) {
    int idx = (blockIdx.x - 12288) * blockDim.x + threadIdx.x;  // 0..65535
    int t = idx >> 5, i = idx & 31;
    float inv = powf(10000.0f, -(float)(2 * i) / 64.0f);
    float a = (float)t * inv;
    cs[idx] = make_float2(cosf(a), sinf(a));
    return;
  }
  int i = blockIdx.x * blockDim.x + threadIdx.x;  // 0..3145727 (float4 units)
  const float* src;
  unsigned short* dst;
  int off;
  if (i < 2097152) { src = x;  dst = xb;  off = i; }
  else if (i < 2883584) { src = wq; dst = wqb; off = i - 2097152; }
  else { src = wo; dst = wob; off = i - 2883584; }
  float4 v = ((const float4*)src)[off];
  ushort4 o;
  o.x = f2bf(v.x); o.y = f2bf(v.y); o.z = f2bf(v.z); o.w = f2bf(v.w);
  ((ushort4*)dst)[off] = o;
}

// ---------------------------------------------------------------- RoPE apply (K only, in-place)
// one thread per 4 pairs (16B): B*T*H*8 = 1048576 threads
__global__ void rope_apply_k(unsigned short* __restrict__ qkv,
                             const float2* __restrict__ cs) {
  int idx = blockIdx.x * blockDim.x + threadIdx.x;
  int i4 = idx & 7;
  int h = (idx >> 3) & 15;
  int t = (idx >> 7) & 2047;
  int b = idx >> 18;
  unsigned short* p =
      qkv + ((size_t)((b << 11) + t)) * 3072 + 1024 + h * 64 + i4 * 8;
  bf16x8 v = *(const bf16x8*)p;
  const float2* c4 = cs + (t << 5) + i4 * 4;
#pragma unroll
  for (int j = 0; j < 4; ++j) {
    const float2 cn = c4[j];
    const float e = bf2f((unsigned short)v[2 * j]);
    const float o = bf2f((unsigned short)v[2 * j + 1]);
    v[2 * j]     = (short)f2bf(e * cn.x - o * cn.y);
    v[2 * j + 1] = (short)f2bf(e * cn.y + o * cn.x);
  }
  *(bf16x8*)p = v;
}

// ---------------------------------------------------------------- GEMM phased: counted-vmcnt ring
// BM=256, BN=128, BK=64; 512 thr = 8 waves (2M x 4N), per-wave out 128x32.
// Ring of 3 K-half buffers; phase j: wait half j, frag ds_reads, stage half
// j+2, MFMA. vmcnt(3) counted (never 0 until last).  [R14-verified order]
template <int OUT_BF16>
__global__ __launch_bounds__(512, 2) void gemm_bt_p(
    const unsigned short* __restrict__ A, const unsigned short* __restrict__ B,
    const float* __restrict__ bias, void* __restrict__ Cout,
    int M, int N, int K) {
  __shared__ unsigned short lA[3 * 8192];   // 3 x 128 lines x 64 elems (16 KB)
  __shared__ unsigned short lB[3 * 4096];   // 3 x  64 lines x 64 elems ( 8 KB)

  const int tiles_n = N >> 7;
  const int swz = (blockIdx.x & 7) * (gridDim.x >> 3) + (blockIdx.x >> 3);
  const int bm = swz / tiles_n;
  const int bn = swz % tiles_n;
  const int m0 = bm << 8, n0 = bn << 7;
  const int tid = threadIdx.x;
  const int w = tid >> 6, l = tid & 63;
  const int l15 = l & 15, lq = l >> 4;      // lq 0..3
  const int wm = w >> 2, wn = w & 3;        // 2 x 4 waves

  const int sl8 = l >> 3, sc = l & 7;       // staging: lane row/chunk in 8x8

  f32x4 acc[8][2] = {};

#define STAGE_HALF(J, RS)                                                     \
  if ((J) < 32) {                                                             \
    const int k0_ = (J) * 32;                                                 \
    _Pragma("unroll")                                                         \
    for (int i_ = 0; i_ < 2; ++i_) {                                          \
      const int line = i_ * 64 + w * 8 + sl8;                                 \
      const int lc = sc ^ (line & 7);                                         \
      const int row = 2 * line + (lc >> 2);                                   \
      gload_lds16(A + (size_t)(m0 + row) * K + k0_ + (lc & 3) * 8,            \
                  &lA[(RS) * 8192 + line * 64 + sc * 8]);                     \
    }                                                                         \
    {                                                                         \
      const int line = w * 8 + sl8;                                           \
      const int lc = sc ^ (line & 7);                                         \
      const int row = 2 * line + (lc >> 2);                                   \
      gload_lds16(B + (size_t)(n0 + row) * K + k0_ + (lc & 3) * 8,            \
                  &lB[(RS) * 4096 + line * 64 + sc * 8]);                     \
    }                                                                         \
  }

  STAGE_HALF(0, 0);
  STAGE_HALF(1, 1);

  int rb = 0;          // ring slot of half j
  for (int j = 0; j < 32; ++j) {
    if (j < 31)
      asm volatile("s_waitcnt vmcnt(3)" ::: "memory");
    else
      asm volatile("s_waitcnt vmcnt(0)" ::: "memory");
    __builtin_amdgcn_s_barrier();

    bf16x8 af[8], bfr[2];
#pragma unroll
    for (int mi = 0; mi < 8; ++mi) {
      const int row = wm * 128 + mi * 16 + l15;
      const int line = row >> 1;
      const int pc = (((row & 1) * 4 + lq) ^ (line & 7));
      af[mi] = *(const bf16x8*)&lA[rb * 8192 + line * 64 + pc * 8];
    }
#pragma unroll
    for (int ni = 0; ni < 2; ++ni) {
      const int row = wn * 32 + ni * 16 + l15;
      const int line = row >> 1;
      const int pc = (((row & 1) * 4 + lq) ^ (line & 7));
      bfr[ni] = *(const bf16x8*)&lB[rb * 4096 + line * 64 + pc * 8];
    }

    const int rs = rb == 0 ? 2 : rb - 1;    // (rb+2)%3
    STAGE_HALF(j + 2, rs);

    __builtin_amdgcn_s_setprio(1);
#pragma unroll
    for (int mi = 0; mi < 8; ++mi)
#pragma unroll
      for (int ni = 0; ni < 2; ++ni)
        acc[mi][ni] = __builtin_amdgcn_mfma_f32_16x16x32_bf16(
            af[mi], bfr[ni], acc[mi][ni], 0, 0, 0);
    __builtin_amdgcn_s_setprio(0);

    rb = rb == 2 ? 0 : rb + 1;
  }
#undef STAGE_HALF

#pragma unroll
  for (int ni = 0; ni < 2; ++ni) {
    const int c = n0 + wn * 32 + ni * 16 + l15;
    const float bv = bias[c];
#pragma unroll
    for (int mi = 0; mi < 8; ++mi) {
#pragma unroll
      for (int jj = 0; jj < 4; ++jj) {
        const int r = m0 + wm * 128 + mi * 16 + lq * 4 + jj;
        const float v = acc[mi][ni][jj] + bv;
        if (OUT_BF16)
          ((unsigned short*)Cout)[(size_t)r * N + c] = f2bf(v);
        else
          ((float*)Cout)[(size_t)r * N + c] = v;
      }
    }
  }
}

// ---------------------------------------------------------------- flash attention fwd
// v21 == v17/v19 exactly (verified 99.5 us / ~199 total): 8-wave, single-S,
// sequential softmax -> PACKPV -> V drain; V swizzle k^(d&0x38).
#define PACKPV(SCV, KS)                                                        \
  do {                                                                         \
    unsigned xa, xb, ya, yb;                                                   \
    asm("v_cvt_pk_bf16_f32 %0, %1, %2"                                         \
        : "=v"(xa) : "v"(SCV[((KS) & 1) * 8 + 0]), "v"(SCV[((KS) & 1) * 8 + 1])); \
    asm("v_cvt_pk_bf16_f32 %0, %1, %2"                                         \
        : "=v"(xb) : "v"(SCV[((KS) & 1) * 8 + 2]), "v"(SCV[((KS) & 1) * 8 + 3])); \
    asm("v_cvt_pk_bf16_f32 %0, %1, %2"                                         \
        : "=v"(ya) : "v"(SCV[((KS) & 1) * 8 + 4]), "v"(SCV[((KS) & 1) * 8 + 5])); \
    asm("v_cvt_pk_bf16_f32 %0, %1, %2"                                         \
        : "=v"(yb) : "v"(SCV[((KS) & 1) * 8 + 6]), "v"(SCV[((KS) & 1) * 8 + 7])); \
    asm("v_permlane32_swap_b32 %0, %1" : "+v"(xa), "+v"(ya));                  \
    asm("v_permlane32_swap_b32 %0, %1" : "+v"(xb), "+v"(yb));                  \
    u32x4 pw;                                                                  \
    pw[0] = xa; pw[1] = xb; pw[2] = ya; pw[3] = yb;                            \
    const bf16x8 pa = __builtin_bit_cast(bf16x8, pw);                          \
    {                                                                          \
      const bf16x8 vf = *(const bf16x8*)                                       \
          &lVc[l31 * 72 + ((16 * (KS) + 8 * hi) ^ (l31 & 0x38))];              \
      o0 = __builtin_amdgcn_mfma_f32_32x32x16_bf16(pa, vf, o0, 0, 0, 0);       \
    }                                                                          \
    {                                                                          \
      const int vrow = 32 + l31;                                               \
      const bf16x8 vf = *(const bf16x8*)                                       \
          &lVc[vrow * 72 + ((16 * (KS) + 8 * hi) ^ (vrow & 0x38))];            \
      o1 = __builtin_amdgcn_mfma_f32_32x32x16_bf16(pa, vf, o1, 0, 0, 0);       \
    }                                                                          \
  } while (0)

__global__ __launch_bounds__(512, 4) void attn_fwd(
    const unsigned short* __restrict__ qkv, unsigned short* __restrict__ aout,
    const float2* __restrict__ cs) {
  __shared__ unsigned short lK[2 * 64 * 64];    // K tiles, chunk-XOR-swizzled
  __shared__ unsigned short lVt[2 * 64 * 72];   // V^T, stride 72, k ^ (d&0x38)

  const int g = blockIdx.x;
  const int xcd = g & 7;
  const int j2 = g >> 3;                 // 0..63
  const int bh = ((j2 >> 3) << 3) + xcd; // 0..63
  const int qt = j2 & 7;
  const int h = bh & 15, b = bh >> 4;

  const int tid = threadIdx.x;
  const int w = tid >> 6, l = tid & 63;  // 8 waves
  const int l31 = l & 31, hi = l >> 5;
  const int l7 = l & 7;

  const size_t bt_base = (size_t)(b * 2048) * 3072;
  const int qbase = qt * 256 + w * 32;

  const unsigned short* Qp =
      qkv + bt_base + (size_t)(qbase + l31) * 3072 + h * 64 + hi * 8;
  const float2* csrow = cs + (size_t)(qbase + l31) * 32;
  bf16x8 qf[4];
#pragma unroll
  for (int s = 0; s < 4; ++s) {
    bf16x8 q = *(const bf16x8*)(Qp + 16 * s);
#pragma unroll
    for (int j = 0; j < 4; ++j) {
      const float2 cn = csrow[8 * s + 4 * hi + j];
      const float e = bf2f((unsigned short)q[2 * j]);
      const float o = bf2f((unsigned short)q[2 * j + 1]);
      q[2 * j]     = (short)f2bf((e * cn.x - o * cn.y) * 0.125f);
      q[2 * j + 1] = (short)f2bf((e * cn.y + o * cn.x) * 0.125f);
    }
    qf[s] = q;
  }

  const unsigned short* Kp = qkv + bt_base + 1024 + h * 64;
  const unsigned short* Vp = qkv + bt_base + 2048 + h * 64;

  const int krow = l >> 3;
  const int kcol = ((l & 7) ^ (l >> 3)) << 3;

  const int vr = tid >> 3;             // 0..63
  const int vc0 = (tid & 7) << 3;      // 0,8,..,56
  const int vx = vc0;                  // write swizzle: k ^ (d & 0x38)

  f32x16 o0 = {}, o1 = {};
  float m_run = -1e30f, lsum = 0.f;
  bf16x8 v0;
  const float L2E = 1.4426950408889634f;

  {
    gload_lds16(Kp + (size_t)(w * 8 + krow) * 3072 + kcol, &lK[(w * 8) * 64]);
    const unsigned short* vb = Vp + (size_t)vr * 3072 + vc0;
    v0 = *(const bf16x8*)vb;
  }
  __syncthreads();
#pragma unroll
  for (int i2 = 0; i2 < 8; ++i2)
    lVt[(vc0 + i2) * 72 + (vr ^ vx)] = (unsigned short)v0[i2];
  __syncthreads();

  for (int t = 0; t < 32; ++t) {
    const int cur = t & 1;
    const unsigned short* lKc = lK + cur * 4096;
    const unsigned short* lVc = lVt + cur * 4608;
    const bool stage = (t < 31);

    if (stage) {
      const unsigned short* kb = Kp + (size_t)(t + 1) * 64 * 3072;
      gload_lds16(kb + (size_t)(w * 8 + krow) * 3072 + kcol,
                  lK + (cur ^ 1) * 4096 + (w * 8) * 64);
    }

    f32x16 s0 = {}, s1 = {};
    __builtin_amdgcn_s_setprio(1);
#pragma unroll
    for (int s = 0; s < 4; ++s) {
      bf16x8 kf = *(const bf16x8*)&lKc[l31 * 64 + (((2 * s + hi) ^ l7) << 3)];
      s0 = __builtin_amdgcn_mfma_f32_32x32x16_bf16(kf, qf[s], s0, 0, 0, 0);
    }
#pragma unroll
    for (int s = 0; s < 4; ++s) {
      bf16x8 kf = *(const bf16x8*)&lKc[(32 + l31) * 64 + (((2 * s + hi) ^ l7) << 3)];
      s1 = __builtin_amdgcn_mfma_f32_32x32x16_bf16(kf, qf[s], s1, 0, 0, 0);
    }
    __builtin_amdgcn_s_setprio(0);

    if (stage) {
      const unsigned short* vb =
          Vp + (size_t)(t + 1) * 64 * 3072 + (size_t)vr * 3072 + vc0;
      v0 = *(const bf16x8*)vb;
    }

    {
      float pmax = -1e30f;
#pragma unroll
      for (int r = 0; r < 16; r += 2) {
        float t0, t1;
        asm("v_max3_f32 %0, %1, %2, %3"
            : "=v"(t0) : "v"(s0[r]), "v"(s0[r + 1]), "v"(pmax));
        asm("v_max3_f32 %0, %1, %2, %3"
            : "=v"(t1) : "v"(s1[r]), "v"(s1[r + 1]), "v"(t0));
        pmax = t1;
      }
      pmax = fmaxf(pmax, __shfl_xor(pmax, 32));
      if (!__all(pmax <= m_run + 8.0f)) {
        const float mn = fmaxf(m_run, pmax);
        const float alpha = __expf(m_run - mn);
        m_run = mn;
        lsum *= alpha;
#pragma unroll
        for (int r = 0; r < 16; ++r) {
          const float ar = __shfl(alpha, (r & 3) + 8 * (r >> 2) + 4 * hi);
          o0[r] *= ar;
          o1[r] *= ar;
        }
      }
      const float m2 = m_run * L2E;
      float rsa = 0.f, rsb = 0.f;
#pragma unroll
      for (int r = 0; r < 16; r += 2) {
        float a0 = __builtin_fmaf(s0[r], L2E, -m2);
        float a1 = __builtin_fmaf(s0[r + 1], L2E, -m2);
        float p0, p1;
        asm("v_exp_f32 %0, %1" : "=v"(p0) : "v"(a0));
        asm("v_exp_f32 %0, %1" : "=v"(p1) : "v"(a1));
        s0[r] = p0; s0[r + 1] = p1; rsa += p0; rsb += p1;
        a0 = __builtin_fmaf(s1[r], L2E, -m2);
        a1 = __builtin_fmaf(s1[r + 1], L2E, -m2);
        asm("v_exp_f32 %0, %1" : "=v"(p0) : "v"(a0));
        asm("v_exp_f32 %0, %1" : "=v"(p1) : "v"(a1));
        s1[r] = p0; s1[r + 1] = p1; rsa += p0; rsb += p1;
      }
      float rs = rsa + rsb;
      rs += __shfl_xor(rs, 32);
      lsum += rs;
    }

    __builtin_amdgcn_s_setprio(1);
    PACKPV(s0, 0);
    PACKPV(s0, 1);
    PACKPV(s1, 2);
    PACKPV(s1, 3);
    __builtin_amdgcn_s_setprio(0);

    if (stage) {
      unsigned short* lVn = lVt + (cur ^ 1) * 4608;
#pragma unroll
      for (int i2 = 0; i2 < 8; ++i2)
        lVn[(vc0 + i2) * 72 + (vr ^ vx)] = (unsigned short)v0[i2];
    }
    __syncthreads();
  }

  const float linv = 1.0f / lsum;
#pragma unroll
  for (int r = 0; r < 16; ++r) {
    const int crow = (r & 3) + 8 * (r >> 2) + 4 * hi;
    const float lr = __shfl(linv, crow);
    unsigned short* orow =
        aout + (size_t)(b * 2048 + qbase + crow) * 1024 + h * 64 + l31;
    orow[0] = f2bf(o0[r] * lr);
    orow[32] = f2bf(o1[r] * lr);
  }
}

// ---------------------------------------------------------------- launch
extern "C" void kernel_launch(void* const* d_in, const int* in_sizes, int n_in,
                              void* d_out, int out_size, void* d_ws, size_t ws_size,
                              hipStream_t stream) {
  const float* x     = (const float*)d_in[0];
  const float* w_qkv = (const float*)d_in[1];
  const float* b_qkv = (const float*)d_in[2];
  const float* w_out = (const float*)d_in[3];
  const float* b_out = (const float*)d_in[4];
  float* out = (float*)d_out;

  char* ws = (char*)d_ws;
  unsigned short* x_bf    = (unsigned short*)(ws);             // 16 MB
  unsigned short* wqkv_bf = (unsigned short*)(ws + 16777216);  // 6 MB
  unsigned short* wout_bf = (unsigned short*)(ws + 23068672);  // 2 MB
  unsigned short* qkv     = (unsigned short*)(ws + 25165824);  // 48 MB
  unsigned short* aout    = (unsigned short*)(ws + 75497472);  // 16 MB
  float2* cs              = (float2*)(ws + 92274688);          // 512 KB

  cast3_rope_tbl<<<12544, 256, 0, stream>>>(x, w_qkv, w_out,
                                            x_bf, wqkv_bf, wout_bf, cs);

  // qkv = x @ w_qkv^T + b_qkv  (M=8192, N=3072, K=1024) — phased, 768 blocks
  gemm_bt_p<1><<<768, 512, 0, stream>>>(x_bf, wqkv_bf, b_qkv, qkv,
                                        8192, 3072, 1024);
  rope_apply_k<<<1048576 / 256, 256, 0, stream>>>(qkv, cs);
  attn_fwd<<<512, 512, 0, stream>>>(qkv, aout, cs);
  // out = attn @ w_out^T + b_out (M=8192, N=1024, K=1024) — phased, 256 blocks
  gemm_bt_p<0><<<256, 512, 0, stream>>>(aout, wout_bf, b_out, out,
                                        8192, 1024, 1024);
}